// Round 1
// baseline (753.027 us; speedup 1.0000x reference)
//
#include <hip/hip_runtime.h>

// CorrelationPyramid on MI355X — round 1: correctness-first fp32.
//
// Pipeline:
//   1) proj_kernel : 1x1 conv C=128 -> Co=64, NCHW in -> NHWC out (un-normalized)
//   2) pool_kernel : 2x2 avg-pool chain on un-normalized features (NHWC)
//   3) norm_kernel : per-pixel L2 normalize in place (eps=1e-12, torch-style max(norm,eps))
//   4) corr_kernel : per (bn,h,dy) block; q-row + v-row staged in LDS (c-split halves,
//                    pixel stride 17 float2 -> conflict-free b64 reads); each thread owns
//                    one w and accumulates all (2R+1) dx dots. Roll wraparound via mod.

#define EPSN 1e-12f

// ---------------- projection ----------------
// out[img, p, o] = sum_c W[o,c] * x[img, c, p] + b[o]   (NHWC output)
__global__ __launch_bounds__(256) void proj_kernel(
    const float* __restrict__ x, const float* __restrict__ wt,
    const float* __restrict__ bias, float* __restrict__ out,
    int P, int total) {
  int gid = blockIdx.x * 256 + threadIdx.x;
  if (gid >= total) return;
  int img = gid / P;
  int p = gid - img * P;
  const float* xp = x + (size_t)img * 128 * P + p;
  float acc[64];
#pragma unroll
  for (int o = 0; o < 64; ++o) acc[o] = bias[o];
  for (int c = 0; c < 128; ++c) {
    float xv = xp[(size_t)c * P];           // coalesced across threads (p contiguous)
#pragma unroll
    for (int o = 0; o < 64; ++o) acc[o] = fmaf(wt[o * 128 + c], xv, acc[o]);  // wt: scalar (uniform) loads
  }
  float4* op = (float4*)(out + (size_t)gid * 64);
#pragma unroll
  for (int o = 0; o < 16; ++o)
    op[o] = make_float4(acc[4 * o], acc[4 * o + 1], acc[4 * o + 2], acc[4 * o + 3]);
}

// ---------------- 2x2 avg pool (NHWC, exact mean of 4) ----------------
__global__ __launch_bounds__(256) void pool_kernel(
    const float* __restrict__ in, float* __restrict__ out,
    int Hi, int Wi, int total) {  // total = nimg*Ho*Wo*16 (float4 units)
  int gid = blockIdx.x * 256 + threadIdx.x;
  if (gid >= total) return;
  int Ho = Hi >> 1, Wo = Wi >> 1;
  int c4 = gid & 15;
  int rest = gid >> 4;
  int wo = rest % Wo; rest /= Wo;
  int ho = rest % Ho;
  int img = rest / Ho;
  const float4* in4 = (const float4*)in;
  size_t i00 = (((size_t)img * Hi + 2 * ho) * Wi + 2 * wo) * 16 + c4;
  float4 a = in4[i00];
  float4 b = in4[i00 + 16];
  float4 c = in4[i00 + (size_t)Wi * 16];
  float4 d = in4[i00 + (size_t)Wi * 16 + 16];
  float4 r;
  r.x = 0.25f * (a.x + b.x + c.x + d.x);
  r.y = 0.25f * (a.y + b.y + c.y + d.y);
  r.z = 0.25f * (a.z + b.z + c.z + d.z);
  r.w = 0.25f * (a.w + b.w + c.w + d.w);
  ((float4*)out)[gid] = r;
}

// ---------------- per-pixel L2 normalize in place ----------------
__global__ __launch_bounds__(256) void norm_kernel(float* __restrict__ buf, int npix) {
  int gid = blockIdx.x * 256 + threadIdx.x;
  if (gid >= npix) return;
  float4* p = (float4*)buf + (size_t)gid * 16;
  float4 v[16];
  float ss = 0.f;
#pragma unroll
  for (int i = 0; i < 16; ++i) {
    v[i] = p[i];
    ss = fmaf(v[i].x, v[i].x, ss);
    ss = fmaf(v[i].y, v[i].y, ss);
    ss = fmaf(v[i].z, v[i].z, ss);
    ss = fmaf(v[i].w, v[i].w, ss);
  }
  float s = 1.0f / fmaxf(sqrtf(ss), EPSN);
#pragma unroll
  for (int i = 0; i < 16; ++i)
    p[i] = make_float4(v[i].x * s, v[i].y * s, v[i].z * s, v[i].w * s);
}

// ---------------- correlation ----------------
// One block per (bn, h, dyi). Stages the q row (b,h) and the rolled v row
// (bn, (h-dy) mod H) into LDS in two channel-halves (32 ch each).
// LDS pixel stride = 17 float2 (34 floats): bank stride 2 mod 32 -> each bank
// serves exactly 4 words per wave b64 access = conflict-free minimum.
// Thread w computes all D=2R+1 dx outputs: out[bn,h,w, dyi*D + dxi].
template <int R>
__global__ void corr_kernel(const float* __restrict__ qn, const float* __restrict__ vn,
                            float* __restrict__ out, int H, int W, int N) {
  constexpr int D = 2 * R + 1;
  extern __shared__ float lds[];
  float2* sq = (float2*)lds;   // [W][17]
  float2* sv = sq + W * 17;    // [W][17]

  int idx = blockIdx.x;
  int dyi = idx % D; idx /= D;
  int h = idx % H; idx /= H;
  int bn = idx;          // 0..B*N-1
  int b = bn / N;

  int h2 = h - (dyi - R);                 // (h - dy) mod H, |dy|<=R<H
  if (h2 < 0) h2 += H; else if (h2 >= H) h2 -= H;

  const float2* qrow = (const float2*)(qn + ((size_t)(b * H + h) * W) * 64);
  const float2* vrow = (const float2*)(vn + ((size_t)(bn * H + h2) * W) * 64);

  int w = threadIdx.x;
  float acc[D];
#pragma unroll
  for (int i = 0; i < D; ++i) acc[i] = 0.f;

  for (int half = 0; half < 2; ++half) {
    // stage 32 channels of both rows (coalesced float2 loads)
    for (int i = threadIdx.x; i < W * 16; i += blockDim.x) {
      int ww = i >> 4, c2 = i & 15;
      sq[ww * 17 + c2] = qrow[ww * 32 + half * 16 + c2];
      sv[ww * 17 + c2] = vrow[ww * 32 + half * 16 + c2];
    }
    __syncthreads();
    if (w < W) {
      float2 qr[16];
      const float2* sqp = sq + w * 17;
#pragma unroll
      for (int j = 0; j < 16; ++j) qr[j] = sqp[j];
#pragma unroll
      for (int dxi = 0; dxi < D; ++dxi) {
        int wc = w - (dxi - R);             // (w - dx) mod W
        if (wc < 0) wc += W; else if (wc >= W) wc -= W;
        const float2* svp = sv + wc * 17;
        float s = acc[dxi];
#pragma unroll
        for (int j = 0; j < 16; ++j) {
          float2 vv = svp[j];
          s = fmaf(qr[j].x, vv.x, s);
          s = fmaf(qr[j].y, vv.y, s);
        }
        acc[dxi] = s;
      }
    }
    __syncthreads();
  }

  if (w < W) {
    float* op = out + ((size_t)(bn * H + h) * W + w) * (D * D) + (size_t)dyi * D;
#pragma unroll
    for (int dxi = 0; dxi < D; ++dxi) op[dxi] = acc[dxi];
  }
}

extern "C" void kernel_launch(void* const* d_in, const int* in_sizes, int n_in,
                              void* d_out, int out_size, void* d_ws, size_t ws_size,
                              hipStream_t stream) {
  const float* query  = (const float*)d_in[0];   // [2,128,160,160]
  const float* values = (const float*)d_in[1];   // [2,4,128,160,160]
  const float* pw     = (const float*)d_in[2];   // [64,128]
  const float* pb     = (const float*)d_in[3];   // [64]
  float* out = (float*)d_out;
  float* ws  = (float*)d_ws;

  const int B = 2, N = 4;
  const int P0 = 160 * 160;  // 25600

  // workspace layout (floats), NHWC per level — total 21,760,000 floats = 87 MB
  float* q0 = ws;
  float* v0 = q0 + (size_t)B * P0 * 64;
  float* q1 = v0 + (size_t)B * N * P0 * 64;
  float* v1 = q1 + (size_t)B * (P0 / 4) * 64;
  float* q2 = v1 + (size_t)B * N * (P0 / 4) * 64;
  float* v2 = q2 + (size_t)B * (P0 / 16) * 64;
  float* q3 = v2 + (size_t)B * N * (P0 / 16) * 64;
  float* v3 = q3 + (size_t)B * (P0 / 64) * 64;

  // 1) projection (un-normalized, NHWC)
  {
    int tq = B * P0;
    proj_kernel<<<(tq + 255) / 256, 256, 0, stream>>>(query, pw, pb, q0, P0, tq);
    int tv = B * N * P0;
    proj_kernel<<<(tv + 255) / 256, 256, 0, stream>>>(values, pw, pb, v0, P0, tv);
  }
  // 2) pooling chain on un-normalized features
  {
    int t;
    t = B * (P0 / 4) * 16;      pool_kernel<<<(t + 255) / 256, 256, 0, stream>>>(q0, q1, 160, 160, t);
    t = B * N * (P0 / 4) * 16;  pool_kernel<<<(t + 255) / 256, 256, 0, stream>>>(v0, v1, 160, 160, t);
    t = B * (P0 / 16) * 16;     pool_kernel<<<(t + 255) / 256, 256, 0, stream>>>(q1, q2, 80, 80, t);
    t = B * N * (P0 / 16) * 16; pool_kernel<<<(t + 255) / 256, 256, 0, stream>>>(v1, v2, 80, 80, t);
    t = B * (P0 / 64) * 16;     pool_kernel<<<(t + 255) / 256, 256, 0, stream>>>(q2, q3, 40, 40, t);
    t = B * N * (P0 / 64) * 16; pool_kernel<<<(t + 255) / 256, 256, 0, stream>>>(v2, v3, 40, 40, t);
  }
  // 3) normalize all levels in place
  {
    int t;
    t = B * P0;          norm_kernel<<<(t + 255) / 256, 256, 0, stream>>>(q0, t);
    t = B * N * P0;      norm_kernel<<<(t + 255) / 256, 256, 0, stream>>>(v0, t);
    t = B * P0 / 4;      norm_kernel<<<(t + 255) / 256, 256, 0, stream>>>(q1, t);
    t = B * N * P0 / 4;  norm_kernel<<<(t + 255) / 256, 256, 0, stream>>>(v1, t);
    t = B * P0 / 16;     norm_kernel<<<(t + 255) / 256, 256, 0, stream>>>(q2, t);
    t = B * N * P0 / 16; norm_kernel<<<(t + 255) / 256, 256, 0, stream>>>(v2, t);
    t = B * P0 / 64;     norm_kernel<<<(t + 255) / 256, 256, 0, stream>>>(q3, t);
    t = B * N * P0 / 64; norm_kernel<<<(t + 255) / 256, 256, 0, stream>>>(v3, t);
  }
  // 4) correlation per level (output tuple concatenated flat)
  float* out0 = out;
  float* out1 = out0 + (size_t)B * N * P0 * 81;
  float* out2 = out1 + (size_t)B * N * (P0 / 4) * 25;
  float* out3 = out2 + (size_t)B * N * (P0 / 16) * 9;
  corr_kernel<4><<<B * N * 160 * 9, 192, 272 * 160, stream>>>(q0, v0, out0, 160, 160, N);
  corr_kernel<2><<<B * N * 80 * 5, 128, 272 * 80, stream>>>(q1, v1, out1, 80, 80, N);
  corr_kernel<1><<<B * N * 40 * 3, 64, 272 * 40, stream>>>(q2, v2, out2, 40, 40, N);
  corr_kernel<1><<<B * N * 20 * 3, 64, 272 * 20, stream>>>(q3, v3, out3, 20, 20, N);
}

// Round 2
// 504.303 us; speedup vs baseline: 1.4932x; 1.4932x over previous
//
#include <hip/hip_runtime.h>

// CorrelationPyramid on MI355X — round 2: MFMA Gram-band for level 0.
//
// Pipeline (10 dispatches):
//   1) proj_kernel  : 1x1 conv C=128 -> 64, NCHW -> NHWC fp32, q+v merged
//   2) pool_kernel  x3 : 2x2 avg pool chain (q&v contiguous per level)
//   3) norm16_kernel: level-0 features -> L2-normalized f16 NHWC
//   4) norm32_kernel: levels 1-3 L2-normalized fp32 in place
//   5) corr0_mfma   : level 0 via mfma_f32_16x16x32_f16 on the +/-4 band of Q.V^T
//   6) corr_kernel  x3 : scalar LDS path for levels 1-3 (small)

typedef _Float16 f16;
typedef _Float16 f16x8 __attribute__((ext_vector_type(8)));
typedef float f32x4 __attribute__((ext_vector_type(4)));

#define EPSN 1e-12f

// ---------------- projection (merged query + values) ----------------
__global__ __launch_bounds__(256) void proj_kernel(
    const float* __restrict__ xq, const float* __restrict__ xv,
    const float* __restrict__ wt, const float* __restrict__ bias,
    float* __restrict__ out, int P, int total) {
  int gid = blockIdx.x * 256 + threadIdx.x;
  if (gid >= total) return;
  int img = gid / P;
  int p = gid - img * P;
  const float* xp = (img < 2) ? (xq + (size_t)img * 128 * P + p)
                              : (xv + (size_t)(img - 2) * 128 * P + p);
  float acc[64];
#pragma unroll
  for (int o = 0; o < 64; ++o) acc[o] = bias[o];
  for (int c = 0; c < 128; ++c) {
    float xv_ = xp[(size_t)c * P];
#pragma unroll
    for (int o = 0; o < 64; ++o) acc[o] = fmaf(wt[o * 128 + c], xv_, acc[o]);
  }
  float4* op = (float4*)(out + (size_t)gid * 64);
#pragma unroll
  for (int o = 0; o < 16; ++o)
    op[o] = make_float4(acc[4 * o], acc[4 * o + 1], acc[4 * o + 2], acc[4 * o + 3]);
}

// ---------------- 2x2 avg pool (NHWC) ----------------
__global__ __launch_bounds__(256) void pool_kernel(
    const float* __restrict__ in, float* __restrict__ out,
    int Hi, int Wi, int total) {
  int gid = blockIdx.x * 256 + threadIdx.x;
  if (gid >= total) return;
  int Ho = Hi >> 1, Wo = Wi >> 1;
  int c4 = gid & 15;
  int rest = gid >> 4;
  int wo = rest % Wo; rest /= Wo;
  int ho = rest % Ho;
  int img = rest / Ho;
  const float4* in4 = (const float4*)in;
  size_t i00 = (((size_t)img * Hi + 2 * ho) * Wi + 2 * wo) * 16 + c4;
  float4 a = in4[i00];
  float4 b = in4[i00 + 16];
  float4 c = in4[i00 + (size_t)Wi * 16];
  float4 d = in4[i00 + (size_t)Wi * 16 + 16];
  float4 r;
  r.x = 0.25f * (a.x + b.x + c.x + d.x);
  r.y = 0.25f * (a.y + b.y + c.y + d.y);
  r.z = 0.25f * (a.z + b.z + c.z + d.z);
  r.w = 0.25f * (a.w + b.w + c.w + d.w);
  ((float4*)out)[gid] = r;
}

// ---------------- fp32 in-place L2 normalize (levels 1-3) ----------------
__global__ __launch_bounds__(256) void norm32_kernel(float* __restrict__ buf, int npix) {
  int gid = blockIdx.x * 256 + threadIdx.x;
  if (gid >= npix) return;
  float4* p = (float4*)buf + (size_t)gid * 16;
  float4 v[16];
  float ss = 0.f;
#pragma unroll
  for (int i = 0; i < 16; ++i) {
    v[i] = p[i];
    ss = fmaf(v[i].x, v[i].x, ss);
    ss = fmaf(v[i].y, v[i].y, ss);
    ss = fmaf(v[i].z, v[i].z, ss);
    ss = fmaf(v[i].w, v[i].w, ss);
  }
  float s = 1.0f / fmaxf(sqrtf(ss), EPSN);
#pragma unroll
  for (int i = 0; i < 16; ++i)
    p[i] = make_float4(v[i].x * s, v[i].y * s, v[i].z * s, v[i].w * s);
}

// ---------------- level-0: fp32 -> normalized f16 ----------------
__global__ __launch_bounds__(256) void norm16_kernel(
    const float* __restrict__ in, f16* __restrict__ out, int npix) {
  int gid = blockIdx.x * 256 + threadIdx.x;
  if (gid >= npix) return;
  const float4* p = (const float4*)in + (size_t)gid * 16;
  float4 v[16];
  float ss = 0.f;
#pragma unroll
  for (int i = 0; i < 16; ++i) {
    v[i] = p[i];
    ss = fmaf(v[i].x, v[i].x, ss);
    ss = fmaf(v[i].y, v[i].y, ss);
    ss = fmaf(v[i].z, v[i].z, ss);
    ss = fmaf(v[i].w, v[i].w, ss);
  }
  float s = 1.0f / fmaxf(sqrtf(ss), EPSN);
  f16x8* o8 = (f16x8*)(out + (size_t)gid * 64);
#pragma unroll
  for (int i = 0; i < 8; ++i) {
    float4 a = v[2 * i], b = v[2 * i + 1];
    f16x8 h;
    h[0] = (f16)(a.x * s); h[1] = (f16)(a.y * s);
    h[2] = (f16)(a.z * s); h[3] = (f16)(a.w * s);
    h[4] = (f16)(b.x * s); h[5] = (f16)(b.y * s);
    h[6] = (f16)(b.z * s); h[7] = (f16)(b.w * s);
    o8[i] = h;
  }
}

// ---------------- level-0 correlation via MFMA Gram band ----------------
// Block = (bn, h, dyg) where dyg covers dyi = 3*dyg..3*dyg+2. 320 threads = 5 waves;
// wave wv owns w-tiles {2wv, 2wv+1} (W=160 -> 10 tiles of 16).
// For each (w-tile, dyi): out[w][dxi] = Q[w] . V[h2][(w - dxi + 4) mod W], the +/-4
// band of the tile-row of Q.V^T -> 3 MFMA 16x16 tiles (v-tiles twt-1, twt, twt+1).
// LDS: q row + 3 v rows, K-chunked (32 ch), pixel slot = 40 f16 (32 data + 8 pad,
// 80 B -> 20-word stride, gcd(20,32)=4 -> near-even bank spread for b128 frags).
#define SPIX 40

__global__ __launch_bounds__(320, 4) void corr0_mfma(
    const f16* __restrict__ qh, const f16* __restrict__ vh,
    float* __restrict__ out, int N) {
  const int W = 160, H = 160;
  __shared__ f16 lds[4 * 160 * SPIX];  // 51,200 B

  int idx = blockIdx.x;
  int dyg = idx % 3; idx /= 3;
  int h = idx % H; idx /= H;
  int bn = idx;            // 0..B*N-1
  int b = bn / N;

  int tid = threadIdx.x;
  int lane = tid & 63;
  int wv = tid >> 6;       // 0..4
  int cl = lane & 15;
  int quad = lane >> 4;

  const f16* qrow = qh + ((size_t)(b * H + h) * W) * 64;

  f32x4 acc[2][3][3];
#pragma unroll
  for (int a = 0; a < 2; ++a)
#pragma unroll
    for (int d = 0; d < 3; ++d)
#pragma unroll
      for (int t = 0; t < 3; ++t) acc[a][d][t] = (f32x4)0.f;

  for (int chunk = 0; chunk < 2; ++chunk) {
    // stage q row + 3 v rows (32-channel chunk) as 16B units
    for (int it = tid; it < 4 * 160 * 4; it += 320) {
      int j = it & 3;
      int pix = (it >> 2) % 160;
      int r = it / (160 * 4);
      const f16* src;
      if (r == 0) {
        src = qrow;
      } else {
        int dyi = 3 * dyg + (r - 1);
        int h2 = h - dyi + 4;
        if (h2 < 0) h2 += H; else if (h2 >= H) h2 -= H;
        src = vh + ((size_t)(bn * H + h2) * W) * 64;
      }
      *(uint4*)(lds + (r * 160 + pix) * SPIX + j * 8) =
          *(const uint4*)(src + (size_t)pix * 64 + chunk * 32 + j * 8);
    }
    __syncthreads();

    f16x8 afr[2];
#pragma unroll
    for (int wt = 0; wt < 2; ++wt) {
      int w = (2 * wv + wt) * 16 + cl;    // A row m
      afr[wt] = *(const f16x8*)(lds + (size_t)w * SPIX + quad * 8);
    }
#pragma unroll
    for (int dl = 0; dl < 3; ++dl) {
#pragma unroll
      for (int vt = 0; vt < 4; ++vt) {
        int tvi = 2 * wv - 1 + vt;        // -1..10
        int tw = tvi; if (tw < 0) tw += 10; else if (tw >= 10) tw -= 10;
        int c = tw * 16 + cl;             // B col n (pixel)
        f16x8 bfr = *(const f16x8*)(lds + ((size_t)(1 + dl) * 160 + c) * SPIX + quad * 8);
        if (vt < 3)
          acc[0][dl][vt] = __builtin_amdgcn_mfma_f32_16x16x32_f16(afr[0], bfr, acc[0][dl][vt], 0, 0, 0);
        if (vt > 0)
          acc[1][dl][vt - 1] = __builtin_amdgcn_mfma_f32_16x16x32_f16(afr[1], bfr, acc[1][dl][vt - 1], 0, 0, 0);
      }
    }
    __syncthreads();
  }

  // epilogue: D tile entry (row=quad*4+r, col=cl); dxi = w - c_unwrapped + 4
#pragma unroll
  for (int wt = 0; wt < 2; ++wt) {
    int twt = 2 * wv + wt;
    int w0 = twt * 16;
#pragma unroll
    for (int dl = 0; dl < 3; ++dl) {
      int dyi = 3 * dyg + dl;
#pragma unroll
      for (int vt = 0; vt < 3; ++vt) {
        int cunw = (twt - 1 + vt) * 16 + cl;
#pragma unroll
        for (int r = 0; r < 4; ++r) {
          int w = w0 + quad * 4 + r;
          int dxi = w - cunw + 4;
          if (dxi >= 0 && dxi <= 8)
            out[(((size_t)bn * H + h) * W + w) * 81 + dyi * 9 + dxi] = acc[wt][dl][vt][r];
        }
      }
    }
  }
}

// ---------------- scalar correlation (levels 1-3) ----------------
template <int R>
__global__ void corr_kernel(const float* __restrict__ qn, const float* __restrict__ vn,
                            float* __restrict__ out, int H, int W, int N) {
  constexpr int D = 2 * R + 1;
  extern __shared__ float ldsf[];
  float2* sq = (float2*)ldsf;
  float2* sv = sq + W * 17;

  int idx = blockIdx.x;
  int dyi = idx % D; idx /= D;
  int h = idx % H; idx /= H;
  int bn = idx;
  int b = bn / N;

  int h2 = h - (dyi - R);
  if (h2 < 0) h2 += H; else if (h2 >= H) h2 -= H;

  const float2* qrow = (const float2*)(qn + ((size_t)(b * H + h) * W) * 64);
  const float2* vrow = (const float2*)(vn + ((size_t)(bn * H + h2) * W) * 64);

  int w = threadIdx.x;
  float acc[D];
#pragma unroll
  for (int i = 0; i < D; ++i) acc[i] = 0.f;

  for (int half = 0; half < 2; ++half) {
    for (int i = threadIdx.x; i < W * 16; i += blockDim.x) {
      int ww = i >> 4, c2 = i & 15;
      sq[ww * 17 + c2] = qrow[ww * 32 + half * 16 + c2];
      sv[ww * 17 + c2] = vrow[ww * 32 + half * 16 + c2];
    }
    __syncthreads();
    if (w < W) {
      float2 qr[16];
      const float2* sqp = sq + w * 17;
#pragma unroll
      for (int j = 0; j < 16; ++j) qr[j] = sqp[j];
#pragma unroll
      for (int dxi = 0; dxi < D; ++dxi) {
        int wc = w - (dxi - R);
        if (wc < 0) wc += W; else if (wc >= W) wc -= W;
        const float2* svp = sv + wc * 17;
        float s = acc[dxi];
#pragma unroll
        for (int j = 0; j < 16; ++j) {
          float2 vv = svp[j];
          s = fmaf(qr[j].x, vv.x, s);
          s = fmaf(qr[j].y, vv.y, s);
        }
        acc[dxi] = s;
      }
    }
    __syncthreads();
  }

  if (w < W) {
    float* op = out + ((size_t)(bn * H + h) * W + w) * (D * D) + (size_t)dyi * D;
#pragma unroll
    for (int dxi = 0; dxi < D; ++dxi) op[dxi] = acc[dxi];
  }
}

extern "C" void kernel_launch(void* const* d_in, const int* in_sizes, int n_in,
                              void* d_out, int out_size, void* d_ws, size_t ws_size,
                              hipStream_t stream) {
  const float* query  = (const float*)d_in[0];   // [2,128,160,160]
  const float* values = (const float*)d_in[1];   // [2,4,128,160,160]
  const float* pw     = (const float*)d_in[2];   // [64,128]
  const float* pb     = (const float*)d_in[3];   // [64]
  float* out = (float*)d_out;
  float* ws  = (float*)d_ws;

  const int B = 2, N = 4;
  const int P0 = 160 * 160;

  // fp32 NHWC features (contiguous: q0,v0,q1,v1,q2,v2,q3,v3)
  float* q0 = ws;
  float* v0 = q0 + (size_t)B * P0 * 64;
  float* q1 = v0 + (size_t)B * N * P0 * 64;
  float* v1 = q1 + (size_t)B * (P0 / 4) * 64;
  float* q2 = v1 + (size_t)B * N * (P0 / 4) * 64;
  float* v2 = q2 + (size_t)B * (P0 / 16) * 64;
  float* q3 = v2 + (size_t)B * N * (P0 / 16) * 64;
  float* v3 = q3 + (size_t)B * (P0 / 64) * 64;
  float* fend = v3 + (size_t)B * N * (P0 / 64) * 64;  // 21,760,000 floats
  // f16 normalized level-0 features (contiguous q0h,v0h)
  f16* q0h = (f16*)fend;
  f16* v0h = q0h + (size_t)B * P0 * 64;

  // 1) projection: 10 images in one dispatch
  {
    int t = (B + B * N) * P0;
    proj_kernel<<<(t + 255) / 256, 256, 0, stream>>>(query, values, pw, pb, q0, P0, t);
  }
  // 2) pooling chain (q&v contiguous per level -> one dispatch per level)
  {
    int t;
    t = 10 * (P0 / 4) * 16;   pool_kernel<<<(t + 255) / 256, 256, 0, stream>>>(q0, q1, 160, 160, t);
    t = 10 * (P0 / 16) * 16;  pool_kernel<<<(t + 255) / 256, 256, 0, stream>>>(q1, q2, 80, 80, t);
    t = 10 * (P0 / 64) * 16;  pool_kernel<<<(t + 255) / 256, 256, 0, stream>>>(q2, q3, 40, 40, t);
  }
  // 3) level-0 normalized f16; levels 1-3 normalized fp32 in place
  {
    int t = 10 * P0;
    norm16_kernel<<<(t + 255) / 256, 256, 0, stream>>>(q0, q0h, t);
    t = 10 * (P0 / 4 + P0 / 16 + P0 / 64);
    norm32_kernel<<<(t + 255) / 256, 256, 0, stream>>>(q1, t);
  }
  // 4) correlation
  float* out0 = out;
  float* out1 = out0 + (size_t)B * N * P0 * 81;
  float* out2 = out1 + (size_t)B * N * (P0 / 4) * 25;
  float* out3 = out2 + (size_t)B * N * (P0 / 16) * 9;
  corr0_mfma<<<B * N * 160 * 3, 320, 0, stream>>>(q0h, v0h, out0, N);
  corr_kernel<2><<<B * N * 80 * 5, 128, 272 * 80, stream>>>(q1, v1, out1, 80, 80, N);
  corr_kernel<1><<<B * N * 40 * 3, 64, 272 * 40, stream>>>(q2, v2, out2, 40, 40, N);
  corr_kernel<1><<<B * N * 20 * 3, 64, 272 * 20, stream>>>(q3, v3, out3, 20, 20, N);
}

// Round 3
// 393.614 us; speedup vs baseline: 1.9131x; 1.2812x over previous
//
#include <hip/hip_runtime.h>

// CorrelationPyramid on MI355X — round 3: MFMA projection w/ fused level-0 norm.
//
// Pipeline (9 dispatches):
//   1) proj_mfma    : 1x1 conv C=128 -> 64 via mfma_f32_16x16x32_f16.
//                     Per block: 128 px x 128 ch x-tile staged fp32->f16 (transposed)
//                     in LDS, W tile in LDS. Epilogue adds bias, writes fp32 NHWC
//                     (for pooling) AND L2-normalized f16 NHWC (for corr0) — the
//                     round-2 norm16_kernel is fused away.
//   2) pool_kernel x3 : 2x2 avg pool chain (q&v contiguous per level)
//   3) norm32_kernel: levels 1-3 L2-normalized fp32 in place
//   4) corr0_mfma   : level 0 via mfma on the +/-4 band of Q.V^T
//   5) corr_kernel x3 : scalar LDS path for levels 1-3

typedef _Float16 f16;
typedef _Float16 f16x4 __attribute__((ext_vector_type(4)));
typedef _Float16 f16x8 __attribute__((ext_vector_type(8)));
typedef float f32x4 __attribute__((ext_vector_type(4)));

#define EPSN 1e-12f

// ---------------- projection via MFMA, fused level-0 normalize ----------------
// Block: 256 threads (4 waves), 128 pixels, all 64 outputs, K=128.
// LDS x-tile: [128 px][stride 136 f16]  (b128 r/w land uniformly on banks)
// LDS w-tile: [64 o  ][stride 136 f16]
// Wave wv owns px-tiles {2wv, 2wv+1}; all 4 o-tiles; acc[2][4] f32x4.
#define XS 136

__global__ __launch_bounds__(256, 3) void proj_mfma(
    const float* __restrict__ xq, const float* __restrict__ xv,
    const float* __restrict__ wt, const float* __restrict__ bias,
    float* __restrict__ outf, f16* __restrict__ outh, int P) {
  __shared__ f16 xs[128 * XS];   // 34,816 B
  __shared__ f16 ws[64 * XS];    // 17,408 B

  int bid = blockIdx.x;
  int img = bid / 200;           // 10 images: 0,1 = query; 2..9 = values
  int p0 = (bid - img * 200) * 128;
  const float* xsrc = (img < 2) ? (xq + (size_t)img * 128 * P)
                                : (xv + (size_t)(img - 2) * 128 * P);

  int tid = threadIdx.x;
  int lane = tid & 63;
  int wv = tid >> 6;
  int cl = lane & 15;
  int quad = lane >> 4;

  // ---- stage weights: 64 o x 16 groups of 8 ch = 1024 b128 units ----
  for (int it = tid; it < 64 * 16; it += 256) {
    int o = it >> 4, g = it & 15;
    float4 w0 = *(const float4*)(wt + o * 128 + g * 8);
    float4 w1 = *(const float4*)(wt + o * 128 + g * 8 + 4);
    f16x8 h;
    h[0] = (f16)w0.x; h[1] = (f16)w0.y; h[2] = (f16)w0.z; h[3] = (f16)w0.w;
    h[4] = (f16)w1.x; h[5] = (f16)w1.y; h[6] = (f16)w1.z; h[7] = (f16)w1.w;
    *(f16x8*)(ws + o * XS + g * 8) = h;
  }

  // ---- stage x-tile transposed: thread = (pixel, 64-ch half); 8 iters x 8 ch ----
  {
    int pxs = tid & 127;
    int c0 = (tid >> 7) * 64;
    const float* xp = xsrc + (size_t)c0 * P + p0 + pxs;
#pragma unroll
    for (int i = 0; i < 8; ++i) {
      float v[8];
#pragma unroll
      for (int k = 0; k < 8; ++k) v[k] = xp[(size_t)(8 * i + k) * P];
      f16x8 h;
#pragma unroll
      for (int k = 0; k < 8; ++k) h[k] = (f16)v[k];
      *(f16x8*)(xs + pxs * XS + c0 + 8 * i) = h;
    }
  }
  __syncthreads();

  // ---- MFMA: D[m=o][n=px] ----
  f32x4 acc[2][4];
#pragma unroll
  for (int a = 0; a < 2; ++a)
#pragma unroll
    for (int m = 0; m < 4; ++m) acc[a][m] = (f32x4)0.f;

#pragma unroll
  for (int kc = 0; kc < 4; ++kc) {
    f16x8 bfr[2], afr[4];
#pragma unroll
    for (int pt = 0; pt < 2; ++pt) {
      int px = (2 * wv + pt) * 16 + cl;
      bfr[pt] = *(const f16x8*)(xs + px * XS + kc * 32 + quad * 8);
    }
#pragma unroll
    for (int mt = 0; mt < 4; ++mt) {
      int o = mt * 16 + cl;
      afr[mt] = *(const f16x8*)(ws + o * XS + kc * 32 + quad * 8);
    }
#pragma unroll
    for (int pt = 0; pt < 2; ++pt)
#pragma unroll
      for (int mt = 0; mt < 4; ++mt)
        acc[pt][mt] = __builtin_amdgcn_mfma_f32_16x16x32_f16(afr[mt], bfr[pt], acc[pt][mt], 0, 0, 0);
  }

  // ---- epilogue: +bias, write fp32; reduce ||.||, write normalized f16 ----
  float4 bi[4];
#pragma unroll
  for (int mt = 0; mt < 4; ++mt) bi[mt] = *(const float4*)(bias + mt * 16 + quad * 4);

#pragma unroll
  for (int pt = 0; pt < 2; ++pt) {
    int px = p0 + (2 * wv + pt) * 16 + cl;
    float ss = 0.f;
#pragma unroll
    for (int mt = 0; mt < 4; ++mt) {
      acc[pt][mt][0] += bi[mt].x;
      acc[pt][mt][1] += bi[mt].y;
      acc[pt][mt][2] += bi[mt].z;
      acc[pt][mt][3] += bi[mt].w;
#pragma unroll
      for (int r = 0; r < 4; ++r) ss = fmaf(acc[pt][mt][r], acc[pt][mt][r], ss);
    }
    ss += __shfl_xor(ss, 16, 64);
    ss += __shfl_xor(ss, 32, 64);
    float s = 1.0f / fmaxf(sqrtf(ss), EPSN);
    size_t base = ((size_t)img * P + px) * 64;
#pragma unroll
    for (int mt = 0; mt < 4; ++mt) {
      *(float4*)(outf + base + mt * 16 + quad * 4) =
          make_float4(acc[pt][mt][0], acc[pt][mt][1], acc[pt][mt][2], acc[pt][mt][3]);
      f16x4 hn;
      hn[0] = (f16)(acc[pt][mt][0] * s);
      hn[1] = (f16)(acc[pt][mt][1] * s);
      hn[2] = (f16)(acc[pt][mt][2] * s);
      hn[3] = (f16)(acc[pt][mt][3] * s);
      *(f16x4*)(outh + base + mt * 16 + quad * 4) = hn;
    }
  }
}

// ---------------- 2x2 avg pool (NHWC) ----------------
__global__ __launch_bounds__(256) void pool_kernel(
    const float* __restrict__ in, float* __restrict__ out,
    int Hi, int Wi, int total) {
  int gid = blockIdx.x * 256 + threadIdx.x;
  if (gid >= total) return;
  int Ho = Hi >> 1, Wo = Wi >> 1;
  int c4 = gid & 15;
  int rest = gid >> 4;
  int wo = rest % Wo; rest /= Wo;
  int ho = rest % Ho;
  int img = rest / Ho;
  const float4* in4 = (const float4*)in;
  size_t i00 = (((size_t)img * Hi + 2 * ho) * Wi + 2 * wo) * 16 + c4;
  float4 a = in4[i00];
  float4 b = in4[i00 + 16];
  float4 c = in4[i00 + (size_t)Wi * 16];
  float4 d = in4[i00 + (size_t)Wi * 16 + 16];
  float4 r;
  r.x = 0.25f * (a.x + b.x + c.x + d.x);
  r.y = 0.25f * (a.y + b.y + c.y + d.y);
  r.z = 0.25f * (a.z + b.z + c.z + d.z);
  r.w = 0.25f * (a.w + b.w + c.w + d.w);
  ((float4*)out)[gid] = r;
}

// ---------------- fp32 in-place L2 normalize (levels 1-3) ----------------
__global__ __launch_bounds__(256) void norm32_kernel(float* __restrict__ buf, int npix) {
  int gid = blockIdx.x * 256 + threadIdx.x;
  if (gid >= npix) return;
  float4* p = (float4*)buf + (size_t)gid * 16;
  float4 v[16];
  float ss = 0.f;
#pragma unroll
  for (int i = 0; i < 16; ++i) {
    v[i] = p[i];
    ss = fmaf(v[i].x, v[i].x, ss);
    ss = fmaf(v[i].y, v[i].y, ss);
    ss = fmaf(v[i].z, v[i].z, ss);
    ss = fmaf(v[i].w, v[i].w, ss);
  }
  float s = 1.0f / fmaxf(sqrtf(ss), EPSN);
#pragma unroll
  for (int i = 0; i < 16; ++i)
    p[i] = make_float4(v[i].x * s, v[i].y * s, v[i].z * s, v[i].w * s);
}

// ---------------- level-0 correlation via MFMA Gram band ----------------
#define SPIX 40

__global__ __launch_bounds__(320, 4) void corr0_mfma(
    const f16* __restrict__ qh, const f16* __restrict__ vh,
    float* __restrict__ out, int N) {
  const int W = 160, H = 160;
  __shared__ f16 lds[4 * 160 * SPIX];  // 51,200 B

  int idx = blockIdx.x;
  int dyg = idx % 3; idx /= 3;
  int h = idx % H; idx /= H;
  int bn = idx;
  int b = bn / N;

  int tid = threadIdx.x;
  int lane = tid & 63;
  int wv = tid >> 6;
  int cl = lane & 15;
  int quad = lane >> 4;

  const f16* qrow = qh + ((size_t)(b * H + h) * W) * 64;

  f32x4 acc[2][3][3];
#pragma unroll
  for (int a = 0; a < 2; ++a)
#pragma unroll
    for (int d = 0; d < 3; ++d)
#pragma unroll
      for (int t = 0; t < 3; ++t) acc[a][d][t] = (f32x4)0.f;

  for (int chunk = 0; chunk < 2; ++chunk) {
    for (int it = tid; it < 4 * 160 * 4; it += 320) {
      int j = it & 3;
      int pix = (it >> 2) % 160;
      int r = it / (160 * 4);
      const f16* src;
      if (r == 0) {
        src = qrow;
      } else {
        int dyi = 3 * dyg + (r - 1);
        int h2 = h - dyi + 4;
        if (h2 < 0) h2 += H; else if (h2 >= H) h2 -= H;
        src = vh + ((size_t)(bn * H + h2) * W) * 64;
      }
      *(uint4*)(lds + (r * 160 + pix) * SPIX + j * 8) =
          *(const uint4*)(src + (size_t)pix * 64 + chunk * 32 + j * 8);
    }
    __syncthreads();

    f16x8 afr[2];
#pragma unroll
    for (int wt = 0; wt < 2; ++wt) {
      int w = (2 * wv + wt) * 16 + cl;
      afr[wt] = *(const f16x8*)(lds + (size_t)w * SPIX + quad * 8);
    }
#pragma unroll
    for (int dl = 0; dl < 3; ++dl) {
#pragma unroll
      for (int vt = 0; vt < 4; ++vt) {
        int tvi = 2 * wv - 1 + vt;
        int tw = tvi; if (tw < 0) tw += 10; else if (tw >= 10) tw -= 10;
        int c = tw * 16 + cl;
        f16x8 bfr = *(const f16x8*)(lds + ((size_t)(1 + dl) * 160 + c) * SPIX + quad * 8);
        if (vt < 3)
          acc[0][dl][vt] = __builtin_amdgcn_mfma_f32_16x16x32_f16(afr[0], bfr, acc[0][dl][vt], 0, 0, 0);
        if (vt > 0)
          acc[1][dl][vt - 1] = __builtin_amdgcn_mfma_f32_16x16x32_f16(afr[1], bfr, acc[1][dl][vt - 1], 0, 0, 0);
      }
    }
    __syncthreads();
  }

#pragma unroll
  for (int wt = 0; wt < 2; ++wt) {
    int twt = 2 * wv + wt;
    int w0 = twt * 16;
#pragma unroll
    for (int dl = 0; dl < 3; ++dl) {
      int dyi = 3 * dyg + dl;
#pragma unroll
      for (int vt = 0; vt < 3; ++vt) {
        int cunw = (twt - 1 + vt) * 16 + cl;
#pragma unroll
        for (int r = 0; r < 4; ++r) {
          int w = w0 + quad * 4 + r;
          int dxi = w - cunw + 4;
          if (dxi >= 0 && dxi <= 8)
            out[(((size_t)bn * H + h) * W + w) * 81 + dyi * 9 + dxi] = acc[wt][dl][vt][r];
        }
      }
    }
  }
}

// ---------------- scalar correlation (levels 1-3) ----------------
template <int R>
__global__ void corr_kernel(const float* __restrict__ qn, const float* __restrict__ vn,
                            float* __restrict__ out, int H, int W, int N) {
  constexpr int D = 2 * R + 1;
  extern __shared__ float ldsf[];
  float2* sq = (float2*)ldsf;
  float2* sv = sq + W * 17;

  int idx = blockIdx.x;
  int dyi = idx % D; idx /= D;
  int h = idx % H; idx /= H;
  int bn = idx;
  int b = bn / N;

  int h2 = h - (dyi - R);
  if (h2 < 0) h2 += H; else if (h2 >= H) h2 -= H;

  const float2* qrow = (const float2*)(qn + ((size_t)(b * H + h) * W) * 64);
  const float2* vrow = (const float2*)(vn + ((size_t)(bn * H + h2) * W) * 64);

  int w = threadIdx.x;
  float acc[D];
#pragma unroll
  for (int i = 0; i < D; ++i) acc[i] = 0.f;

  for (int half = 0; half < 2; ++half) {
    for (int i = threadIdx.x; i < W * 16; i += blockDim.x) {
      int ww = i >> 4, c2 = i & 15;
      sq[ww * 17 + c2] = qrow[ww * 32 + half * 16 + c2];
      sv[ww * 17 + c2] = vrow[ww * 32 + half * 16 + c2];
    }
    __syncthreads();
    if (w < W) {
      float2 qr[16];
      const float2* sqp = sq + w * 17;
#pragma unroll
      for (int j = 0; j < 16; ++j) qr[j] = sqp[j];
#pragma unroll
      for (int dxi = 0; dxi < D; ++dxi) {
        int wc = w - (dxi - R);
        if (wc < 0) wc += W; else if (wc >= W) wc -= W;
        const float2* svp = sv + wc * 17;
        float s = acc[dxi];
#pragma unroll
        for (int j = 0; j < 16; ++j) {
          float2 vv = svp[j];
          s = fmaf(qr[j].x, vv.x, s);
          s = fmaf(qr[j].y, vv.y, s);
        }
        acc[dxi] = s;
      }
    }
    __syncthreads();
  }

  if (w < W) {
    float* op = out + ((size_t)(bn * H + h) * W + w) * (D * D) + (size_t)dyi * D;
#pragma unroll
    for (int dxi = 0; dxi < D; ++dxi) op[dxi] = acc[dxi];
  }
}

extern "C" void kernel_launch(void* const* d_in, const int* in_sizes, int n_in,
                              void* d_out, int out_size, void* d_ws, size_t ws_size,
                              hipStream_t stream) {
  const float* query  = (const float*)d_in[0];   // [2,128,160,160]
  const float* values = (const float*)d_in[1];   // [2,4,128,160,160]
  const float* pw     = (const float*)d_in[2];   // [64,128]
  const float* pb     = (const float*)d_in[3];   // [64]
  float* out = (float*)d_out;
  float* ws  = (float*)d_ws;

  const int B = 2, N = 4;
  const int P0 = 160 * 160;

  float* q0 = ws;
  float* v0 = q0 + (size_t)B * P0 * 64;
  float* q1 = v0 + (size_t)B * N * P0 * 64;
  float* v1 = q1 + (size_t)B * (P0 / 4) * 64;
  float* q2 = v1 + (size_t)B * N * (P0 / 4) * 64;
  float* v2 = q2 + (size_t)B * (P0 / 16) * 64;
  float* q3 = v2 + (size_t)B * N * (P0 / 16) * 64;
  float* v3 = q3 + (size_t)B * N * 0 + (size_t)B * (P0 / 64) * 64 + (v2 - q3) * 0 + (size_t)0;  // placeholder fixed below
  v3 = q3 + (size_t)B * (P0 / 64) * 64;
  float* fend = v3 + (size_t)B * N * (P0 / 64) * 64;
  f16* q0h = (f16*)fend;
  f16* v0h = q0h + (size_t)B * P0 * 64;

  // 1) projection via MFMA, fused level-0 norm+f16 (10 imgs, 2000 blocks)
  proj_mfma<<<2000, 256, 0, stream>>>(query, values, pw, pb, q0, q0h, P0);

  // 2) pooling chain
  {
    int t;
    t = 10 * (P0 / 4) * 16;   pool_kernel<<<(t + 255) / 256, 256, 0, stream>>>(q0, q1, 160, 160, t);
    t = 10 * (P0 / 16) * 16;  pool_kernel<<<(t + 255) / 256, 256, 0, stream>>>(q1, q2, 80, 80, t);
    t = 10 * (P0 / 64) * 16;  pool_kernel<<<(t + 255) / 256, 256, 0, stream>>>(q2, q3, 40, 40, t);
  }
  // 3) levels 1-3 normalized fp32 in place
  {
    int t = 10 * (P0 / 4 + P0 / 16 + P0 / 64);
    norm32_kernel<<<(t + 255) / 256, 256, 0, stream>>>(q1, t);
  }
  // 4) correlation
  float* out0 = out;
  float* out1 = out0 + (size_t)B * N * P0 * 81;
  float* out2 = out1 + (size_t)B * N * (P0 / 4) * 25;
  float* out3 = out2 + (size_t)B * N * (P0 / 16) * 9;
  corr0_mfma<<<B * N * 160 * 3, 320, 0, stream>>>(q0h, v0h, out0, N);
  corr_kernel<2><<<B * N * 80 * 5, 128, 272 * 80, stream>>>(q1, v1, out1, 80, 80, N);
  corr_kernel<1><<<B * N * 40 * 3, 64, 272 * 40, stream>>>(q2, v2, out2, 40, 40, N);
  corr_kernel<1><<<B * N * 20 * 3, 64, 272 * 20, stream>>>(q3, v3, out3, 20, 20, N);
}

// Round 4
// 328.168 us; speedup vs baseline: 2.2946x; 1.1994x over previous
//
#include <hip/hip_runtime.h>

// CorrelationPyramid on MI355X — round 4: barrier-free global-MFMA correlation.
//
// Pipeline (9 dispatches):
//   1) proj_mfma   : 1x1 conv C=128 -> 64 via mfma_f32_16x16x32_f16, fused
//                    level-0 L2-normalize + f16 cast in the epilogue.
//   2) pool_kernel x3 : 2x2 avg pool chain on un-normalized fp32 NHWC.
//   3) norm16_kernel  : levels 1-3 fp32 -> L2-normalized f16 (one dispatch;
//                       output aliased into the dead q0-fp32 region).
//   4) corr_mfma<R> x4: one WAVE per (bn, h, w-tile). No LDS, no barriers.
//                    A-frags (q) loaded once from global; per dy: 4 B-frag
//                    global_load_dwordx4 + 4 MFMAs on two shifted band tiles
//                    (cols w0-R and w0+R; D rows 0-7 from T0, 8-15 from T1).
//                    bn = blockIdx%8 pins each 3.28 MB value image to one
//                    XCD's L2 (round-robin dispatch heuristic; perf-only).

typedef _Float16 f16;
typedef _Float16 f16x4 __attribute__((ext_vector_type(4)));
typedef _Float16 f16x8 __attribute__((ext_vector_type(8)));
typedef float f32x4 __attribute__((ext_vector_type(4)));

#define EPSN 1e-12f

// ---------------- projection via MFMA, fused level-0 normalize ----------------
#define XS 136

__global__ __launch_bounds__(256, 3) void proj_mfma(
    const float* __restrict__ xq, const float* __restrict__ xv,
    const float* __restrict__ wt, const float* __restrict__ bias,
    float* __restrict__ outf, f16* __restrict__ outh, int P) {
  __shared__ f16 xs[128 * XS];   // 34,816 B
  __shared__ f16 ws[64 * XS];    // 17,408 B

  int bid = blockIdx.x;
  int img = bid / 200;           // 10 images: 0,1 = query; 2..9 = values
  int p0 = (bid - img * 200) * 128;
  const float* xsrc = (img < 2) ? (xq + (size_t)img * 128 * P)
                                : (xv + (size_t)(img - 2) * 128 * P);

  int tid = threadIdx.x;
  int lane = tid & 63;
  int wv = tid >> 6;
  int cl = lane & 15;
  int quad = lane >> 4;

  for (int it = tid; it < 64 * 16; it += 256) {
    int o = it >> 4, g = it & 15;
    float4 w0 = *(const float4*)(wt + o * 128 + g * 8);
    float4 w1 = *(const float4*)(wt + o * 128 + g * 8 + 4);
    f16x8 h;
    h[0] = (f16)w0.x; h[1] = (f16)w0.y; h[2] = (f16)w0.z; h[3] = (f16)w0.w;
    h[4] = (f16)w1.x; h[5] = (f16)w1.y; h[6] = (f16)w1.z; h[7] = (f16)w1.w;
    *(f16x8*)(ws + o * XS + g * 8) = h;
  }

  {
    int pxs = tid & 127;
    int c0 = (tid >> 7) * 64;
    const float* xp = xsrc + (size_t)c0 * P + p0 + pxs;
#pragma unroll
    for (int i = 0; i < 8; ++i) {
      float v[8];
#pragma unroll
      for (int k = 0; k < 8; ++k) v[k] = xp[(size_t)(8 * i + k) * P];
      f16x8 h;
#pragma unroll
      for (int k = 0; k < 8; ++k) h[k] = (f16)v[k];
      *(f16x8*)(xs + pxs * XS + c0 + 8 * i) = h;
    }
  }
  __syncthreads();

  f32x4 acc[2][4];
#pragma unroll
  for (int a = 0; a < 2; ++a)
#pragma unroll
    for (int m = 0; m < 4; ++m) acc[a][m] = (f32x4)0.f;

#pragma unroll
  for (int kc = 0; kc < 4; ++kc) {
    f16x8 bfr[2], afr[4];
#pragma unroll
    for (int pt = 0; pt < 2; ++pt) {
      int px = (2 * wv + pt) * 16 + cl;
      bfr[pt] = *(const f16x8*)(xs + px * XS + kc * 32 + quad * 8);
    }
#pragma unroll
    for (int mt = 0; mt < 4; ++mt) {
      int o = mt * 16 + cl;
      afr[mt] = *(const f16x8*)(ws + o * XS + kc * 32 + quad * 8);
    }
#pragma unroll
    for (int pt = 0; pt < 2; ++pt)
#pragma unroll
      for (int mt = 0; mt < 4; ++mt)
        acc[pt][mt] = __builtin_amdgcn_mfma_f32_16x16x32_f16(afr[mt], bfr[pt], acc[pt][mt], 0, 0, 0);
  }

  float4 bi[4];
#pragma unroll
  for (int mt = 0; mt < 4; ++mt) bi[mt] = *(const float4*)(bias + mt * 16 + quad * 4);

#pragma unroll
  for (int pt = 0; pt < 2; ++pt) {
    int px = p0 + (2 * wv + pt) * 16 + cl;
    float ss = 0.f;
#pragma unroll
    for (int mt = 0; mt < 4; ++mt) {
      acc[pt][mt][0] += bi[mt].x;
      acc[pt][mt][1] += bi[mt].y;
      acc[pt][mt][2] += bi[mt].z;
      acc[pt][mt][3] += bi[mt].w;
#pragma unroll
      for (int r = 0; r < 4; ++r) ss = fmaf(acc[pt][mt][r], acc[pt][mt][r], ss);
    }
    ss += __shfl_xor(ss, 16, 64);
    ss += __shfl_xor(ss, 32, 64);
    float s = 1.0f / fmaxf(sqrtf(ss), EPSN);
    size_t base = ((size_t)img * P + px) * 64;
#pragma unroll
    for (int mt = 0; mt < 4; ++mt) {
      *(float4*)(outf + base + mt * 16 + quad * 4) =
          make_float4(acc[pt][mt][0], acc[pt][mt][1], acc[pt][mt][2], acc[pt][mt][3]);
      f16x4 hn;
      hn[0] = (f16)(acc[pt][mt][0] * s);
      hn[1] = (f16)(acc[pt][mt][1] * s);
      hn[2] = (f16)(acc[pt][mt][2] * s);
      hn[3] = (f16)(acc[pt][mt][3] * s);
      *(f16x4*)(outh + base + mt * 16 + quad * 4) = hn;
    }
  }
}

// ---------------- 2x2 avg pool (NHWC) ----------------
__global__ __launch_bounds__(256) void pool_kernel(
    const float* __restrict__ in, float* __restrict__ out,
    int Hi, int Wi, int total) {
  int gid = blockIdx.x * 256 + threadIdx.x;
  if (gid >= total) return;
  int Ho = Hi >> 1, Wo = Wi >> 1;
  int c4 = gid & 15;
  int rest = gid >> 4;
  int wo = rest % Wo; rest /= Wo;
  int ho = rest % Ho;
  int img = rest / Ho;
  const float4* in4 = (const float4*)in;
  size_t i00 = (((size_t)img * Hi + 2 * ho) * Wi + 2 * wo) * 16 + c4;
  float4 a = in4[i00];
  float4 b = in4[i00 + 16];
  float4 c = in4[i00 + (size_t)Wi * 16];
  float4 d = in4[i00 + (size_t)Wi * 16 + 16];
  float4 r;
  r.x = 0.25f * (a.x + b.x + c.x + d.x);
  r.y = 0.25f * (a.y + b.y + c.y + d.y);
  r.z = 0.25f * (a.z + b.z + c.z + d.z);
  r.w = 0.25f * (a.w + b.w + c.w + d.w);
  ((float4*)out)[gid] = r;
}

// ---------------- fp32 -> L2-normalized f16 (levels 1-3) ----------------
__global__ __launch_bounds__(256) void norm16_kernel(
    const float* __restrict__ in, f16* __restrict__ out, int npix) {
  int gid = blockIdx.x * 256 + threadIdx.x;
  if (gid >= npix) return;
  const float4* p = (const float4*)in + (size_t)gid * 16;
  float4 v[16];
  float ss = 0.f;
#pragma unroll
  for (int i = 0; i < 16; ++i) {
    v[i] = p[i];
    ss = fmaf(v[i].x, v[i].x, ss);
    ss = fmaf(v[i].y, v[i].y, ss);
    ss = fmaf(v[i].z, v[i].z, ss);
    ss = fmaf(v[i].w, v[i].w, ss);
  }
  float s = 1.0f / fmaxf(sqrtf(ss), EPSN);
  f16x8* o8 = (f16x8*)(out + (size_t)gid * 64);
#pragma unroll
  for (int i = 0; i < 8; ++i) {
    float4 a = v[2 * i], b = v[2 * i + 1];
    f16x8 h;
    h[0] = (f16)(a.x * s); h[1] = (f16)(a.y * s);
    h[2] = (f16)(a.z * s); h[3] = (f16)(a.w * s);
    h[4] = (f16)(b.x * s); h[5] = (f16)(b.y * s);
    h[6] = (f16)(b.z * s); h[7] = (f16)(b.w * s);
    o8[i] = h;
  }
}

// ---------------- correlation: one wave per (bn, h, w-tile) ----------------
// No LDS, no barriers. Band tiles: T0 cols (w0-R+cl) mod W -> D rows 0-7
// (quads 0,1), dxi = r - cl + 2R;  T1 cols (w0+R+cl) mod W -> rows 8-15
// (quads 2,3), dxi = r - cl.  Exact partition for R <= 4. Each (w,dy,dx)
// written exactly once; partial w-tiles (W%16) masked on store.
// C/D layout: col = lane&15, row = (lane>>4)*4 + reg.
template <int R>
__global__ __launch_bounds__(256, 8) void corr_mfma(
    const f16* __restrict__ qh, const f16* __restrict__ vh,
    float* __restrict__ out, int H, int W, int T) {
  constexpr int D = 2 * R + 1, DD = D * D;
  int bn = blockIdx.x & 7;               // 8 bn values -> 8 XCDs (heuristic)
  int wv = threadIdx.x >> 6;
  int widx = (blockIdx.x >> 3) * 4 + wv; // [0, H*T)
  int h = widx / T;
  int wt = widx - h * T;
  int lane = threadIdx.x & 63;
  int cl = lane & 15, quad = lane >> 4;
  int b = bn >> 2;
  int w0 = wt * 16;

  // A fragments (q row), loaded once
  int ap = w0 + cl; if (ap >= W) ap = W - 1;   // clamp partial tile
  const f16* qp = qh + ((size_t)(b * H + h) * W + ap) * 64 + quad * 8;
  f16x8 a0 = *(const f16x8*)qp;
  f16x8 a1 = *(const f16x8*)(qp + 32);

  // B pixel offsets (roll wraparound), fixed across dy
  int c0 = w0 - R + cl; if (c0 < 0) c0 += W; if (c0 >= W) c0 -= W;
  int c1 = w0 + R + cl; if (c1 >= W) c1 -= W;
  int b0off = c0 * 64 + quad * 8;
  int b1off = c1 * 64 + quad * 8;

  // store offsets: out[pix*DD + dyi*D + dxi], pix = (bn*H+h)*W + w
  int rbase = quad * 4;
  int base_dxi = rbase - cl + ((quad < 2) ? 2 * R : 0);
  int wr0 = w0 + rbase;
  int off0 = ((bn * H + h) * W + wr0) * DD + base_dxi;

  for (int dyi = 0; dyi < D; ++dyi) {
    int h2 = h - dyi + R; if (h2 < 0) h2 += H; else if (h2 >= H) h2 -= H;
    const f16* vrow = vh + ((size_t)(bn * H + h2) * W) * 64;
    f16x8 b0a = *(const f16x8*)(vrow + b0off);
    f16x8 b0b = *(const f16x8*)(vrow + b0off + 32);
    f16x8 b1a = *(const f16x8*)(vrow + b1off);
    f16x8 b1b = *(const f16x8*)(vrow + b1off + 32);
    f32x4 A0 = __builtin_amdgcn_mfma_f32_16x16x32_f16(a0, b0a, (f32x4)0.f, 0, 0, 0);
    A0 = __builtin_amdgcn_mfma_f32_16x16x32_f16(a1, b0b, A0, 0, 0, 0);
    f32x4 A1 = __builtin_amdgcn_mfma_f32_16x16x32_f16(a0, b1a, (f32x4)0.f, 0, 0, 0);
    A1 = __builtin_amdgcn_mfma_f32_16x16x32_f16(a1, b1b, A1, 0, 0, 0);
#pragma unroll
    for (int rr = 0; rr < 4; ++rr) {
      int dxi = base_dxi + rr;
      float val = (quad < 2) ? A0[rr] : A1[rr];
      if ((unsigned)dxi <= (unsigned)(2 * R) && (wr0 + rr) < W)
        out[off0 + dyi * D + rr * (DD + 1)] = val;
    }
  }
}

extern "C" void kernel_launch(void* const* d_in, const int* in_sizes, int n_in,
                              void* d_out, int out_size, void* d_ws, size_t ws_size,
                              hipStream_t stream) {
  const float* query  = (const float*)d_in[0];   // [2,128,160,160]
  const float* values = (const float*)d_in[1];   // [2,4,128,160,160]
  const float* pw     = (const float*)d_in[2];   // [64,128]
  const float* pb     = (const float*)d_in[3];   // [64]
  float* out = (float*)d_out;
  float* ws  = (float*)d_ws;

  const int B = 2, N = 4;
  const int P0 = 160 * 160;

  // fp32 un-normalized NHWC pyramid (contiguous q0,v0,q1,v1,q2,v2,q3,v3)
  float* q0 = ws;
  float* v0 = q0 + (size_t)B * P0 * 64;
  float* q1 = v0 + (size_t)B * N * P0 * 64;
  float* v1 = q1 + (size_t)B * (P0 / 4) * 64;
  float* q2 = v1 + (size_t)B * N * (P0 / 4) * 64;
  float* v2 = q2 + (size_t)B * (P0 / 16) * 64;
  float* q3 = v2 + (size_t)B * N * (P0 / 16) * 64;
  float* v3 = q3 + (size_t)B * (P0 / 64) * 64;
  float* fend = v3 + (size_t)B * N * (P0 / 64) * 64;   // 21.76M floats
  // level-0 normalized f16 (written by proj_mfma epilogue)
  f16* q0h = (f16*)fend;
  f16* v0h = q0h + (size_t)B * P0 * 64;
  // levels 1-3 normalized f16: aliased into the dead q0-fp32 region
  // (q0 fp32 is only read by pool1, which runs before norm16_kernel)
  f16* h13 = (f16*)ws;
  f16* qh1 = h13;
  f16* vh1 = qh1 + (size_t)B * (P0 / 4) * 64;
  f16* qh2 = vh1 + (size_t)B * N * (P0 / 4) * 64;
  f16* vh2 = qh2 + (size_t)B * (P0 / 16) * 64;
  f16* qh3 = vh2 + (size_t)B * N * (P0 / 16) * 64;
  f16* vh3 = qh3 + (size_t)B * (P0 / 64) * 64;

  // 1) projection via MFMA, fused level-0 norm+f16
  proj_mfma<<<2000, 256, 0, stream>>>(query, values, pw, pb, q0, q0h, P0);

  // 2) pooling chain (un-normalized fp32)
  {
    int t;
    t = 10 * (P0 / 4) * 16;   pool_kernel<<<(t + 255) / 256, 256, 0, stream>>>(q0, q1, 160, 160, t);
    t = 10 * (P0 / 16) * 16;  pool_kernel<<<(t + 255) / 256, 256, 0, stream>>>(q1, q2, 80, 80, t);
    t = 10 * (P0 / 64) * 16;  pool_kernel<<<(t + 255) / 256, 256, 0, stream>>>(q2, q3, 40, 40, t);
  }
  // 3) levels 1-3 -> normalized f16 (one dispatch; q1..v3 are contiguous)
  {
    int t = 10 * (P0 / 4 + P0 / 16 + P0 / 64);   // 84,000 pixels
    norm16_kernel<<<(t + 255) / 256, 256, 0, stream>>>(q1, h13, t);
  }
  // 4) correlation (output tuple concatenated flat)
  float* out0 = out;
  float* out1 = out0 + (size_t)B * N * P0 * 81;
  float* out2 = out1 + (size_t)B * N * (P0 / 4) * 25;
  float* out3 = out2 + (size_t)B * N * (P0 / 16) * 9;
  // waves = 8*H*T; blocks = waves/4 (all divisible by 8)
  corr_mfma<4><<<8 * 160 * 10 / 4, 256, 0, stream>>>(q0h, v0h, out0, 160, 160, 10);
  corr_mfma<2><<<8 * 80 * 5 / 4, 256, 0, stream>>>(qh1, vh1, out1, 80, 80, 5);
  corr_mfma<1><<<8 * 40 * 3 / 4, 256, 0, stream>>>(qh2, vh2, out2, 40, 40, 3);
  corr_mfma<1><<<8 * 20 * 2 / 4, 256, 0, stream>>>(qh3, vh3, out3, 20, 20, 2);
}